// Round 1
// baseline (1043.160 us; speedup 1.0000x reference)
//
#include <hip/hip_runtime.h>

#define NENT   200000
#define IDIM   128
#define KD     512     // K_FACTORS * GCN_DIM
#define GDIM   128
#define NBATCH 4096

// out layout (floats): sub_emb[4096*512] | rel_emb[4096*512] | x[200000*512] | loss[1]
#define OFF_REL  (NBATCH * KD)            // 2097152
#define OFF_X    (2 * NBATCH * KD)        // 4194304
#define OFF_LOSS (OFF_X + NENT * KD)      // 106594304

__device__ __forceinline__ float fast_tanh(float x) {
    float ax = __builtin_fabsf(x);
    float e  = __expf(-2.0f * ax);
    float r  = __fdividef(1.0f - e, 1.0f + e);
    return __builtin_copysignf(r, x);
}

// ---------------------------------------------------------------------------
// Kernel 1: x = tanh(A @ W + b), A:[200000,128], W:[128,512] -> x:[200000,512]
// 64x64 tile, 256 threads, micro 1x16 (row = t/4, colgroup = t%4).
// ---------------------------------------------------------------------------
__global__ __launch_bounds__(256, 2)
void pca_tanh_kernel(const float* __restrict__ A, const float* __restrict__ W,
                     const float* __restrict__ bias, float* __restrict__ X) {
    __shared__ float As[64 * 129];   // pad 1: A-read bank = (r+k)%32, conflict-free
    __shared__ float Bs[128 * 64];

    const int t  = threadIdx.x;
    const int bx = blockIdx.x;
    const int cb = bx & 7;           // 8 col blocks
    const int rb = bx >> 3;          // 3125 row blocks
    const int r0 = rb * 64;
    const int c0 = cb * 64;

    // stage A tile [64][128] -> As padded (4 scalar writes per float4, ~4-way, once)
#pragma unroll
    for (int i = 0; i < 8; ++i) {
        int f   = t + 256 * i;
        int row = f >> 5;
        int k4  = f & 31;
        float4 v = *(const float4*)(A + (r0 + row) * IDIM + k4 * 4);
        float* dst = As + row * 129 + k4 * 4;
        dst[0] = v.x; dst[1] = v.y; dst[2] = v.z; dst[3] = v.w;
    }
    // stage W tile [128][64] -> Bs (linear, conflict-free)
#pragma unroll
    for (int i = 0; i < 8; ++i) {
        int f  = t + 256 * i;
        int k  = f >> 4;
        int c4 = f & 15;
        *(float4*)(Bs + k * 64 + c4 * 4) = *(const float4*)(W + k * KD + c0 + c4 * 4);
    }

    const int r  = t >> 2;   // tile row 0..63
    const int cg = t & 3;    // col group (16 cols)

    float bb[16];
#pragma unroll
    for (int i = 0; i < 4; ++i) {
        float4 v = *(const float4*)(bias + c0 + cg * 16 + i * 4);
        bb[i * 4 + 0] = v.x; bb[i * 4 + 1] = v.y; bb[i * 4 + 2] = v.z; bb[i * 4 + 3] = v.w;
    }

    __syncthreads();

    float acc[16];
#pragma unroll
    for (int c = 0; c < 16; ++c) acc[c] = 0.0f;

#pragma unroll 8
    for (int k = 0; k < 128; ++k) {
        float a = As[r * 129 + k];
        const float* bp = Bs + k * 64 + cg * 16;
        float4 b0 = *(const float4*)(bp + 0);
        float4 b1 = *(const float4*)(bp + 4);
        float4 b2 = *(const float4*)(bp + 8);
        float4 b3 = *(const float4*)(bp + 12);
        acc[0]  = fmaf(a, b0.x, acc[0]);  acc[1]  = fmaf(a, b0.y, acc[1]);
        acc[2]  = fmaf(a, b0.z, acc[2]);  acc[3]  = fmaf(a, b0.w, acc[3]);
        acc[4]  = fmaf(a, b1.x, acc[4]);  acc[5]  = fmaf(a, b1.y, acc[5]);
        acc[6]  = fmaf(a, b1.z, acc[6]);  acc[7]  = fmaf(a, b1.w, acc[7]);
        acc[8]  = fmaf(a, b2.x, acc[8]);  acc[9]  = fmaf(a, b2.y, acc[9]);
        acc[10] = fmaf(a, b2.z, acc[10]); acc[11] = fmaf(a, b2.w, acc[11]);
        acc[12] = fmaf(a, b3.x, acc[12]); acc[13] = fmaf(a, b3.y, acc[13]);
        acc[14] = fmaf(a, b3.z, acc[14]); acc[15] = fmaf(a, b3.w, acc[15]);
    }

    __syncthreads();   // done reading As/Bs; reuse As as Cs (pitch 68)

    float* Cs = As;    // 64*68 = 4352 floats <= 64*129
#pragma unroll
    for (int i = 0; i < 4; ++i) {
        float4 v;
        v.x = fast_tanh(acc[i * 4 + 0] + bb[i * 4 + 0]);
        v.y = fast_tanh(acc[i * 4 + 1] + bb[i * 4 + 1]);
        v.z = fast_tanh(acc[i * 4 + 2] + bb[i * 4 + 2]);
        v.w = fast_tanh(acc[i * 4 + 3] + bb[i * 4 + 3]);
        *(float4*)(Cs + r * 68 + cg * 16 + i * 4) = v;
    }
    __syncthreads();

    // coalesced store: consecutive lanes -> consecutive 16B, 1KB/instr
#pragma unroll
    for (int p = 0; p < 4; ++p) {
        int f    = t + 256 * p;
        int orow = f >> 4;
        int oc   = f & 15;
        float4 v = *(const float4*)(Cs + orow * 68 + oc * 4);
        *(float4*)(X + (r0 + orow) * KD + c0 + oc * 4) = v;
    }
}

// ---------------------------------------------------------------------------
// Kernel 2: sub_emb = x[sub]; rel_emb = tile(init_rel[rel], 4)
// ---------------------------------------------------------------------------
__global__ void gather_kernel(const float* __restrict__ X, const float* __restrict__ init_rel,
                              const int* __restrict__ sub, const int* __restrict__ rel,
                              float* __restrict__ sub_out, float* __restrict__ rel_out) {
    const int b = blockIdx.x;
    const int t = threadIdx.x;   // 128 threads, one float4 each
    const int s  = sub[b];
    const int rr = rel[b];
    float4 v = *(const float4*)(X + (size_t)s * KD + t * 4);
    *(float4*)(sub_out + (size_t)b * KD + t * 4) = v;
    float4 w = *(const float4*)(init_rel + rr * GDIM + (t & 31) * 4);
    *(float4*)(rel_out + (size_t)b * KD + t * 4) = w;
}

// ---------------------------------------------------------------------------
// Kernel 3a: zero K workspace (ws is poisoned 0xAA every timed call)
// ---------------------------------------------------------------------------
__global__ void zero_ws_kernel(float* __restrict__ ws) {
    ws[blockIdx.x * 256 + threadIdx.x] = 0.0f;   // grid 256 -> 65536 floats
}

// ---------------------------------------------------------------------------
// Kernel 3b: per-factor grams K_k = Z_k^T Z_k (atomic flush).
// grid 64: factor = bx>>4, row chunk (256 rows) = bx&15. micro 8x8.
// ---------------------------------------------------------------------------
__global__ __launch_bounds__(256)
void gram_kernel(const float* __restrict__ sub_emb, float* __restrict__ Kws) {
    const int bx = blockIdx.x;
    const int k     = bx >> 4;
    const int chunk = bx & 15;
    const int t  = threadIdx.x;
    const int td = t & 15, te = t >> 4;
    const int d0 = td * 8, e0 = te * 8;
    const int rbase = chunk * 256;

    float acc[8][8];
#pragma unroll
    for (int i = 0; i < 8; ++i)
#pragma unroll
        for (int j = 0; j < 8; ++j) acc[i][j] = 0.0f;

    for (int r = 0; r < 256; ++r) {
        const float* row = sub_emb + (size_t)(rbase + r) * KD + k * GDIM;
        float4 a0 = *(const float4*)(row + d0);
        float4 a1 = *(const float4*)(row + d0 + 4);
        float4 b0 = *(const float4*)(row + e0);
        float4 b1 = *(const float4*)(row + e0 + 4);
        float av[8] = {a0.x, a0.y, a0.z, a0.w, a1.x, a1.y, a1.z, a1.w};
        float bv[8] = {b0.x, b0.y, b0.z, b0.w, b1.x, b1.y, b1.z, b1.w};
#pragma unroll
        for (int i = 0; i < 8; ++i)
#pragma unroll
            for (int j = 0; j < 8; ++j)
                acc[i][j] = fmaf(av[i], bv[j], acc[i][j]);
    }

    float* Kk = Kws + k * (GDIM * GDIM);
#pragma unroll
    for (int i = 0; i < 8; ++i)
#pragma unroll
        for (int j = 0; j < 8; ++j)
            atomicAdd(&Kk[(d0 + i) * GDIM + (e0 + j)], acc[i][j]);
}

// ---------------------------------------------------------------------------
// Kernel 4: loss = sum_{i<j} sum_{d,f} (K_i[d,f]-c_i[f]) * (K_j[d,f]-c_j[d])
// (K symmetric; c_k[f] = column mean). Single block.
// ---------------------------------------------------------------------------
__global__ __launch_bounds__(256)
void hsic_final_kernel(const float* __restrict__ Kws, float* __restrict__ loss_out) {
    __shared__ float cmean[4 * GDIM];
    __shared__ float red[256];
    const int t = threadIdx.x;

    for (int p = t; p < 4 * GDIM; p += 256) {
        int k = p >> 7, f = p & 127;
        const float* Kk = Kws + k * (GDIM * GDIM);
        float s = 0.0f;
        for (int d = 0; d < GDIM; ++d) s += Kk[d * GDIM + f];
        cmean[p] = s * (1.0f / (float)GDIM);
    }
    __syncthreads();

    float part = 0.0f;
    for (int cell = t; cell < GDIM * GDIM; cell += 256) {
        int d = cell >> 7, f = cell & 127;
        float vi[4], cf[4], cd[4];
#pragma unroll
        for (int k = 0; k < 4; ++k) {
            vi[k] = Kws[k * (GDIM * GDIM) + cell];
            cf[k] = cmean[k * GDIM + f];
            cd[k] = cmean[k * GDIM + d];
        }
#pragma unroll
        for (int i = 0; i < 4; ++i)
#pragma unroll
            for (int j = 0; j < 4; ++j)
                if (j > i) part += (vi[i] - cf[i]) * (vi[j] - cd[j]);
    }

    red[t] = part;
    __syncthreads();
    for (int s = 128; s > 0; s >>= 1) {
        if (t < s) red[t] += red[t + s];
        __syncthreads();
    }
    if (t == 0) loss_out[0] = red[0];
}

// ---------------------------------------------------------------------------
extern "C" void kernel_launch(void* const* d_in, const int* in_sizes, int n_in,
                              void* d_out, int out_size, void* d_ws, size_t ws_size,
                              hipStream_t stream) {
    const float* init_embed = (const float*)d_in[0];
    const float* W_pca      = (const float*)d_in[1];
    const float* b_pca      = (const float*)d_in[2];
    const float* init_rel   = (const float*)d_in[3];
    const int*   sub        = (const int*)d_in[4];
    const int*   rel        = (const int*)d_in[5];

    float* out      = (float*)d_out;
    float* sub_out  = out;
    float* rel_out  = out + OFF_REL;
    float* x_out    = out + OFF_X;
    float* loss_out = out + OFF_LOSS;
    float* Kws      = (float*)d_ws;   // 4*128*128 floats = 256 KB

    zero_ws_kernel<<<256, 256, 0, stream>>>(Kws);
    pca_tanh_kernel<<<(NENT / 64) * (KD / 64), 256, 0, stream>>>(init_embed, W_pca, b_pca, x_out);
    gather_kernel<<<NBATCH, 128, 0, stream>>>(x_out, init_rel, sub, rel, sub_out, rel_out);
    gram_kernel<<<64, 256, 0, stream>>>(sub_out, Kws);
    hsic_final_kernel<<<1, 256, 0, stream>>>(Kws, loss_out);
}

// Round 4
// 741.164 us; speedup vs baseline: 1.4075x; 1.4075x over previous
//
#include <hip/hip_runtime.h>

#define NENT   200000
#define IDIM   128
#define KD     512     // K_FACTORS * GCN_DIM
#define GDIM   128
#define NBATCH 4096

// out layout (floats): sub_emb[4096*512] | rel_emb[4096*512] | x[200000*512] | loss[1]
#define OFF_REL  (NBATCH * KD)
#define OFF_X    (2 * NBATCH * KD)
#define OFF_LOSS (OFF_X + NENT * KD)

// ws layout: Kws f32[4*128*128] (256 KB) | WhT bf16[512*128] (128 KB) | WlT bf16[512*128] (128 KB)
#define WS_WHT_BYTE  262144
#define WS_WLT_BYTE  (262144 + 131072)

typedef __attribute__((ext_vector_type(8))) short  short8;
typedef __attribute__((ext_vector_type(4))) short  short4v;
typedef __attribute__((ext_vector_type(4))) float  f32x4;

__device__ __forceinline__ float fast_tanh(float x) {
    float ax = __builtin_fabsf(x);
    float e  = __expf(-2.0f * ax);
    float r  = __fdividef(1.0f - e, 1.0f + e);
    return __builtin_copysignf(r, x);
}

// truncating fp32 -> bf16 hi/lo split: f ~= hi + lo, |err| <~ 2^-16 |f|
__device__ __forceinline__ void bf16_split(float f, unsigned short& h, unsigned short& l) {
    unsigned u = __float_as_uint(f);
    h = (unsigned short)(u >> 16);
    float r = f - __uint_as_float(u & 0xFFFF0000u);
    l = (unsigned short)(__float_as_uint(r) >> 16);
}

// ---------------------------------------------------------------------------
// Kernel 0: zero Kws (ws is poisoned each timed call)
// ---------------------------------------------------------------------------
__global__ void zero_ws_kernel(float* __restrict__ ws) {
    ws[blockIdx.x * 256 + threadIdx.x] = 0.0f;   // grid 256 -> 65536 floats
}

// ---------------------------------------------------------------------------
// Kernel 1: W transpose + bf16 split.  W[128][512] fp32 -> WhT/WlT[512][128] bf16
// 8192 threads: c = tid&511 (coalesced loads), g = tid>>9 (k-granule of 8)
// ---------------------------------------------------------------------------
__global__ __launch_bounds__(256)
void wprep_kernel(const float* __restrict__ W,
                  unsigned short* __restrict__ WhT, unsigned short* __restrict__ WlT) {
    int tid = blockIdx.x * 256 + threadIdx.x;   // 32 blocks * 256 = 8192
    int c = tid & 511;
    int g = tid >> 9;                           // 0..15
    unsigned short h[8], l[8];
#pragma unroll
    for (int e = 0; e < 8; ++e) {
        float f = W[(g * 8 + e) * KD + c];
        bf16_split(f, h[e], l[e]);
    }
    short8 hv, lv;
#pragma unroll
    for (int e = 0; e < 8; ++e) { hv[e] = (short)h[e]; lv[e] = (short)l[e]; }
    *(short8*)(WhT + c * 128 + g * 8) = hv;
    *(short8*)(WlT + c * 128 + g * 8) = lv;
}

// ---------------------------------------------------------------------------
// Kernel 2: X = tanh(A @ W + b) via bf16x3 MFMA.
// BM=BN=64, K=128 (full), 256 threads = 4 waves, wave tile 32x32 (2x2 frags).
// LDS: Ah|Al|Wh|Wl each [64 rows][128 k] bf16 (256B rows, XOR-swizzled) = 64 KB.
// ---------------------------------------------------------------------------
#define MFMA_BF16 __builtin_amdgcn_mfma_f32_16x16x32_bf16

__global__ __launch_bounds__(256, 2)
void gemm_mfma_kernel(const float* __restrict__ A,
                      const unsigned short* __restrict__ WhT,
                      const unsigned short* __restrict__ WlT,
                      const float* __restrict__ bias,
                      float* __restrict__ X) {
    __shared__ __align__(16) char smem[65536];
    char* Ah = smem;
    char* Al = smem + 16384;
    char* Wh = smem + 32768;
    char* Wl = smem + 49152;

    // bijective XCD-chunked swizzle: 25000 blocks = 8 * 3125
    const int b   = blockIdx.x;
    const int lid = (b & 7) * 3125 + (b >> 3);
    const int rt  = lid >> 3;          // 0..3124 row tile
    const int ct  = lid & 7;           // 0..7 col tile
    const int r0  = rt * 64;
    const int c0  = ct * 64;

    const int t = threadIdx.x;

    // ---- stage A tile [64][128] fp32 -> Ah/Al bf16, swizzled ----
#pragma unroll
    for (int it = 0; it < 8; ++it) {
        int f   = t + 256 * it;        // float4 index, 0..2047
        int row = f >> 5;
        int k4  = f & 31;
        float4 v = *(const float4*)(A + (r0 + row) * IDIM + k4 * 4);
        unsigned short h0, l0, h1, l1, h2, l2, h3, l3;
        bf16_split(v.x, h0, l0); bf16_split(v.y, h1, l1);
        bf16_split(v.z, h2, l2); bf16_split(v.w, h3, l3);
        short4v hv; hv[0] = (short)h0; hv[1] = (short)h1; hv[2] = (short)h2; hv[3] = (short)h3;
        short4v lv; lv[0] = (short)l0; lv[1] = (short)l1; lv[2] = (short)l2; lv[3] = (short)l3;
        int boff = row * 256 + ((k4 * 8) ^ ((row & 7) << 4));
        *(short4v*)(Ah + boff) = hv;
        *(short4v*)(Al + boff) = lv;
    }
    // ---- stage W tile: WhT/WlT rows c0..c0+63 (bf16, [col][k]) -> LDS swizzled ----
#pragma unroll
    for (int it = 0; it < 4; ++it) {
        int f   = t + 256 * it;        // 16B-granule index, 0..1023
        int row = f >> 4;              // local col 0..63
        int g   = f & 15;
        int boff = row * 256 + ((g * 16) ^ ((row & 7) << 4));
        *(short8*)(Wh + boff) = *(const short8*)(WhT + (c0 + row) * 128 + g * 8);
        *(short8*)(Wl + boff) = *(const short8*)(WlT + (c0 + row) * 128 + g * 8);
    }
    __syncthreads();

    const int w  = t >> 6;             // wave 0..3
    const int l  = t & 63;
    const int wr = w >> 1, wc = w & 1; // 2x2 wave grid
    const int lr = l & 15;
    const int lk = l >> 4;             // 0..3
    const int rswz = (lr & 7) << 4;
    const int lk16 = lk * 16;

    const int ar0 = (wr * 32 + lr) * 256;
    const int ar1 = (wr * 32 + 16 + lr) * 256;
    const int bc0 = (wc * 32 + lr) * 256;
    const int bc1 = (wc * 32 + 16 + lr) * 256;

    f32x4 acc[2][2];
#pragma unroll
    for (int i = 0; i < 2; ++i)
#pragma unroll
        for (int j = 0; j < 2; ++j) acc[i][j] = (f32x4)(0.0f);

#pragma unroll
    for (int kk = 0; kk < 4; ++kk) {
        int koff = (kk * 64 + lk16) ^ rswz;
        short8 ah0 = *(const short8*)(Ah + ar0 + koff);
        short8 ah1 = *(const short8*)(Ah + ar1 + koff);
        short8 al0 = *(const short8*)(Al + ar0 + koff);
        short8 al1 = *(const short8*)(Al + ar1 + koff);
        short8 bh0 = *(const short8*)(Wh + bc0 + koff);
        short8 bh1 = *(const short8*)(Wh + bc1 + koff);
        short8 bl0 = *(const short8*)(Wl + bc0 + koff);
        short8 bl1 = *(const short8*)(Wl + bc1 + koff);

        acc[0][0] = MFMA_BF16(ah0, bh0, acc[0][0], 0, 0, 0);
        acc[0][1] = MFMA_BF16(ah0, bh1, acc[0][1], 0, 0, 0);
        acc[1][0] = MFMA_BF16(ah1, bh0, acc[1][0], 0, 0, 0);
        acc[1][1] = MFMA_BF16(ah1, bh1, acc[1][1], 0, 0, 0);

        acc[0][0] = MFMA_BF16(ah0, bl0, acc[0][0], 0, 0, 0);
        acc[0][1] = MFMA_BF16(ah0, bl1, acc[0][1], 0, 0, 0);
        acc[1][0] = MFMA_BF16(ah1, bl0, acc[1][0], 0, 0, 0);
        acc[1][1] = MFMA_BF16(ah1, bl1, acc[1][1], 0, 0, 0);

        acc[0][0] = MFMA_BF16(al0, bh0, acc[0][0], 0, 0, 0);
        acc[0][1] = MFMA_BF16(al0, bh1, acc[0][1], 0, 0, 0);
        acc[1][0] = MFMA_BF16(al1, bh0, acc[1][0], 0, 0, 0);
        acc[1][1] = MFMA_BF16(al1, bh1, acc[1][1], 0, 0, 0);
    }

    // ---- epilogue: bias + tanh, direct stores (64B/quarter-wave segments) ----
#pragma unroll
    for (int j = 0; j < 2; ++j) {
        int col = c0 + wc * 32 + j * 16 + lr;
        float bj = bias[col];
#pragma unroll
        for (int i = 0; i < 2; ++i) {
            int rbase = r0 + wr * 32 + i * 16 + lk * 4;
#pragma unroll
            for (int v = 0; v < 4; ++v) {
                X[(rbase + v) * KD + col] = fast_tanh(acc[i][j][v] + bj);
            }
        }
    }
}

// ---------------------------------------------------------------------------
// Kernel 3: sub_emb = x[sub]; rel_emb = tile(init_rel[rel], 4)
// ---------------------------------------------------------------------------
__global__ void gather_kernel(const float* __restrict__ X, const float* __restrict__ init_rel,
                              const int* __restrict__ sub, const int* __restrict__ rel,
                              float* __restrict__ sub_out, float* __restrict__ rel_out) {
    const int b = blockIdx.x;
    const int t = threadIdx.x;   // 128 threads, one float4 each
    const int s  = sub[b];
    const int rr = rel[b];
    float4 v = *(const float4*)(X + (size_t)s * KD + t * 4);
    *(float4*)(sub_out + (size_t)b * KD + t * 4) = v;
    float4 w = *(const float4*)(init_rel + rr * GDIM + (t & 31) * 4);
    *(float4*)(rel_out + (size_t)b * KD + t * 4) = w;
}

// ---------------------------------------------------------------------------
// Kernel 4: per-factor grams K_k = Z_k^T Z_k, LDS-staged rows.
// grid 64: factor = bx>>4, chunk (256 rows) = bx&15. micro 8x8.
// ---------------------------------------------------------------------------
__global__ __launch_bounds__(256)
void gram_kernel(const float* __restrict__ sub_emb, float* __restrict__ Kws) {
    __shared__ float Zs[32 * 128];    // 16 KB: 32 rows of this factor's 128-slice
    const int bx = blockIdx.x;
    const int k     = bx >> 4;
    const int chunk = bx & 15;
    const int t  = threadIdx.x;
    const int td = t & 15, te = t >> 4;
    const int d0 = td * 8, e0 = te * 8;
    const int rbase = chunk * 256;

    float acc[8][8];
#pragma unroll
    for (int i = 0; i < 8; ++i)
#pragma unroll
        for (int j = 0; j < 8; ++j) acc[i][j] = 0.0f;

    for (int rc = 0; rc < 8; ++rc) {
        // stage 32 rows x 128 floats (coalesced)
#pragma unroll
        for (int it = 0; it < 4; ++it) {
            int f   = t + 256 * it;    // float4 idx 0..1023
            int row = f >> 5;
            int c4  = f & 31;
            *(float4*)(Zs + row * 128 + c4 * 4) =
                *(const float4*)(sub_emb + (size_t)(rbase + rc * 32 + row) * KD + k * GDIM + c4 * 4);
        }
        __syncthreads();
#pragma unroll 2
        for (int r = 0; r < 32; ++r) {
            const float* rp = Zs + r * 128;
            float4 a0 = *(const float4*)(rp + d0);
            float4 a1 = *(const float4*)(rp + d0 + 4);
            float4 b0 = *(const float4*)(rp + e0);
            float4 b1 = *(const float4*)(rp + e0 + 4);
            float av[8] = {a0.x, a0.y, a0.z, a0.w, a1.x, a1.y, a1.z, a1.w};
            float bv[8] = {b0.x, b0.y, b0.z, b0.w, b1.x, b1.y, b1.z, b1.w};
#pragma unroll
            for (int i = 0; i < 8; ++i)
#pragma unroll
                for (int j = 0; j < 8; ++j)
                    acc[i][j] = fmaf(av[i], bv[j], acc[i][j]);
        }
        __syncthreads();
    }

    float* Kk = Kws + k * (GDIM * GDIM);
#pragma unroll
    for (int i = 0; i < 8; ++i)
#pragma unroll
        for (int j = 0; j < 8; ++j)
            atomicAdd(&Kk[(d0 + i) * GDIM + (e0 + j)], acc[i][j]);
}

// ---------------------------------------------------------------------------
// Kernel 5: loss = sum_{i<j} sum_{d,f} (K_i[d,f]-c_i[f]) * (K_j[d,f]-c_j[d])
// ---------------------------------------------------------------------------
__global__ __launch_bounds__(256)
void hsic_final_kernel(const float* __restrict__ Kws, float* __restrict__ loss_out) {
    __shared__ float cmean[4 * GDIM];
    __shared__ float red[256];
    const int t = threadIdx.x;

    for (int p = t; p < 4 * GDIM; p += 256) {
        int k = p >> 7, f = p & 127;
        const float* Kk = Kws + k * (GDIM * GDIM);
        float s = 0.0f;
        for (int d = 0; d < GDIM; ++d) s += Kk[d * GDIM + f];
        cmean[p] = s * (1.0f / (float)GDIM);
    }
    __syncthreads();

    float part = 0.0f;
    for (int cell = t; cell < GDIM * GDIM; cell += 256) {
        int d = cell >> 7, f = cell & 127;
        float vi[4], cf[4], cd[4];
#pragma unroll
        for (int k = 0; k < 4; ++k) {
            vi[k] = Kws[k * (GDIM * GDIM) + cell];
            cf[k] = cmean[k * GDIM + f];
            cd[k] = cmean[k * GDIM + d];
        }
#pragma unroll
        for (int i = 0; i < 4; ++i)
#pragma unroll
            for (int j = 0; j < 4; ++j)
                if (j > i) part += (vi[i] - cf[i]) * (vi[j] - cd[j]);
    }

    red[t] = part;
    __syncthreads();
    for (int s = 128; s > 0; s >>= 1) {
        if (t < s) red[t] += red[t + s];
        __syncthreads();
    }
    if (t == 0) loss_out[0] = red[0];
}

// ---------------------------------------------------------------------------
extern "C" void kernel_launch(void* const* d_in, const int* in_sizes, int n_in,
                              void* d_out, int out_size, void* d_ws, size_t ws_size,
                              hipStream_t stream) {
    const float* init_embed = (const float*)d_in[0];
    const float* W_pca      = (const float*)d_in[1];
    const float* b_pca      = (const float*)d_in[2];
    const float* init_rel   = (const float*)d_in[3];
    const int*   sub        = (const int*)d_in[4];
    const int*   rel        = (const int*)d_in[5];

    float* out      = (float*)d_out;
    float* sub_out  = out;
    float* rel_out  = out + OFF_REL;
    float* x_out    = out + OFF_X;
    float* loss_out = out + OFF_LOSS;

    float*          Kws = (float*)d_ws;
    unsigned short* WhT = (unsigned short*)((char*)d_ws + WS_WHT_BYTE);
    unsigned short* WlT = (unsigned short*)((char*)d_ws + WS_WLT_BYTE);

    zero_ws_kernel<<<256, 256, 0, stream>>>(Kws);
    wprep_kernel<<<32, 256, 0, stream>>>(W_pca, WhT, WlT);
    gemm_mfma_kernel<<<(NENT / 64) * (KD / 64), 256, 0, stream>>>(init_embed, WhT, WlT, b_pca, x_out);
    gather_kernel<<<NBATCH, 128, 0, stream>>>(x_out, init_rel, sub, rel, sub_out, rel_out);
    gram_kernel<<<64, 256, 0, stream>>>(sub_out, Kws);
    hsic_final_kernel<<<1, 256, 0, stream>>>(Kws, loss_out);
}